// Round 5
// baseline (258.492 us; speedup 1.0000x reference)
//
#include <hip/hip_runtime.h>
#include <stdint.h>

#define HIDDEN 1536
#define NHEAD 12
#define HD 128
#define TSEQ 2048
#define NROWS 4096
#define KDIM HIDDEN
#define EPS_F 1.1920928955078125e-07f
// (1/sqrt(128)) * log2(e)
#define SCALE_LOG2E 0.12751879110195655f
// fixed softmax shift (log2 domain): scores bounded by sqrt(128)=11.314 (RMS-normed
// q,k => |q||k|<=128 by Cauchy-Schwarz), *log2(e) = 16.32; use 16.6 for bf16 margin.
#define FIXSUB 16.6f

typedef unsigned short u16;
typedef __bf16 bf16x8_t __attribute__((ext_vector_type(8)));
typedef float f32x4_t __attribute__((ext_vector_type(4)));

#define MFMA16(a, b, c) __builtin_amdgcn_mfma_f32_16x16x32_bf16((a), (b), (c), 0, 0, 0)

__device__ __forceinline__ u16 f2bf(float f) {
  unsigned u = __builtin_bit_cast(unsigned, f);
  u = (u + 0x7fffu + ((u >> 16) & 1u)) >> 16;
  return (u16)u;
}

// ---------------- cast fp32 -> bf16 (vectorized) ----------------
__global__ __launch_bounds__(256) void cast_kernel(const float* __restrict__ in,
                                                   u16* __restrict__ out, int n) {
  int i = (blockIdx.x * 256 + threadIdx.x) * 4;
  if (i >= n) return;
  float4 v = *reinterpret_cast<const float4*>(in + i);
  uint2 pk;
  pk.x = (unsigned)f2bf(v.x) | ((unsigned)f2bf(v.y) << 16);
  pk.y = (unsigned)f2bf(v.z) | ((unsigned)f2bf(v.w) << 16);
  *reinterpret_cast<uint2*>(out + i) = pk;
}

// 4 equal-size weight casts in one launch (blockIdx.y selects)
__global__ __launch_bounds__(256) void cast4_kernel(
    const float* __restrict__ a, const float* __restrict__ b, const float* __restrict__ c,
    const float* __restrict__ d, u16* __restrict__ oa, u16* __restrict__ ob,
    u16* __restrict__ oc, u16* __restrict__ od, int n) {
  const float* in;
  u16* out;
  switch (blockIdx.y) {
    case 0: in = a; out = oa; break;
    case 1: in = b; out = ob; break;
    case 2: in = c; out = oc; break;
    default: in = d; out = od; break;
  }
  int i = (blockIdx.x * 256 + threadIdx.x) * 4;
  if (i >= n) return;
  float4 v = *reinterpret_cast<const float4*>(in + i);
  uint2 pk;
  pk.x = (unsigned)f2bf(v.x) | ((unsigned)f2bf(v.y) << 16);
  pk.y = (unsigned)f2bf(v.z) | ((unsigned)f2bf(v.w) << 16);
  *reinterpret_cast<uint2*>(out + i) = pk;
}

// ---------------- shared NT-GEMM mainloop: C[128x128] = A[128xK] * W[128xK]^T ----------------
// Triple-buffered LDS, prefetch 2 K-tiles ahead, counted vmcnt(8) (loads stay in
// flight across barriers). All matrices leading dim KDIM=1536. bf16 in, fp32 acc.
__device__ __forceinline__ void stage_tile(const u16* __restrict__ src, int row0, int k0,
                                           u16* lds, int w, int l) {
#pragma unroll
  for (int i = 0; i < 2; ++i) {
    int chunk = w * 128 + i * 64 + l;  // 512 chunks of 8 bf16 = 128x32 tile
    int row = chunk >> 2;
    int kc = (chunk & 3) * 8;
    __builtin_amdgcn_global_load_lds(
        (const __attribute__((address_space(1))) void*)(src + (row0 + row) * KDIM + k0 + kc),
        (__attribute__((address_space(3))) void*)(lds + w * 1024 + i * 512), 16, 0, 0);
  }
}

__device__ __forceinline__ void gemm_mainloop(const u16* __restrict__ A,
                                              const u16* __restrict__ W, int M0, int N0,
                                              u16 (*lA)[4096], u16 (*lW)[4096],
                                              f32x4_t acc[4][4], int tid) {
  const int w = tid >> 6, l = tid & 63;
  const int lrow = l & 15, kg = l >> 4;
  const int wr = (w >> 1) * 64, wc = (w & 1) * 64;
  const int NT = KDIM / 32;  // 48
  stage_tile(A, M0, 0, lA[0], w, l);
  stage_tile(W, N0, 0, lW[0], w, l);
  stage_tile(A, M0, 32, lA[1], w, l);
  stage_tile(W, N0, 32, lW[1], w, l);
#pragma unroll 1
  for (int kt = 0; kt < NT; ++kt) {
    const int cur = kt % 3;
    const int nxt = (kt + 2) % 3;
    // clamp dummy prefetch past the end to k0=0 (issued for uniform vmcnt
    // accounting, never consumed; avoids OOB reads past workspace)
    const int kpre = (kt + 2 < NT) ? (kt + 2) * 32 : 0;
    stage_tile(A, M0, kpre, lA[nxt], w, l);
    stage_tile(W, N0, kpre, lW[nxt], w, l);
    asm volatile("s_waitcnt vmcnt(8)" ::: "memory");  // tile kt landed; kt+1,kt+2 in flight
    __builtin_amdgcn_s_barrier();
    asm volatile("" ::: "memory");
    const u16* Ab = lA[cur];
    const u16* Wb = lW[cur];
    bf16x8_t af[4], bf_[4];
#pragma unroll
    for (int m = 0; m < 4; ++m)
      af[m] = *reinterpret_cast<const bf16x8_t*>(Ab + (wr + m * 16 + lrow) * 32 + kg * 8);
#pragma unroll
    for (int n = 0; n < 4; ++n)
      bf_[n] = *reinterpret_cast<const bf16x8_t*>(Wb + (wc + n * 16 + lrow) * 32 + kg * 8);
#pragma unroll
    for (int m = 0; m < 4; ++m)
#pragma unroll
      for (int n = 0; n < 4; ++n)
        acc[m][n] = MFMA16(af[m], bf_[n], acc[m][n]);
    asm volatile("s_waitcnt lgkmcnt(0)" ::: "memory");
    __builtin_amdgcn_s_barrier();
    asm volatile("" ::: "memory");
  }
}

// ---------------- QKV projection (flattened grid, XCD-chunked) ----------------
// 1152 blocks = 32 m-tiles x 12 n-tiles x 3 weights. xcd = wgid&7 round-robins on
// hardware; give each XCD an 8m x 18(nz) rectangle so its A-band (3 MB) stays
// L2-resident and each W-col is fetched once per XCD.
__global__ __launch_bounds__(256) void gemm_qkv_kernel(
    const u16* __restrict__ xb, const u16* __restrict__ wq, const u16* __restrict__ wk,
    const u16* __restrict__ wv, float* __restrict__ qf, float* __restrict__ kf,
    u16* __restrict__ vt) {
  __shared__ __align__(16) u16 lA[3][4096], lW[3][4096];
  const int tid = threadIdx.x;
  const int wgid = blockIdx.x;
  const int xcd = wgid & 7, c = wgid >> 3;          // c in [0,144)
  const int m = ((xcd & 3) << 3) + (c & 7);         // 0..31
  const int nz = ((xcd >> 2) * 18) + (c >> 3);      // 0..35
  const int z = nz / 12, n = nz % 12;
  const int M0 = m * 128, N0 = n * 128;
  const u16* W = (z == 0) ? wq : (z == 1) ? wk : wv;
  f32x4_t acc[4][4] = {};
  gemm_mainloop(xb, W, M0, N0, lA, lW, acc, tid);
  const int w = tid >> 6, l = tid & 63;
  const int lrow = l & 15, kg = l >> 4;
  const int wr = (w >> 1) * 64, wc = (w & 1) * 64;
  const int h = n;  // BN = 128 = HD: one tile column == one head
#pragma unroll
  for (int mi = 0; mi < 4; ++mi)
#pragma unroll
    for (int ni = 0; ni < 4; ++ni)
#pragma unroll
      for (int r = 0; r < 4; ++r) {
        const int grow = M0 + wr + mi * 16 + kg * 4 + r;  // token row in [0,4096)
        const int d = wc + ni * 16 + lrow;                // 0..127 within head
        const int bb = grow >> 11, t = grow & (TSEQ - 1);
        const float v = acc[mi][ni][r];
        if (z == 2) {
          // V stored transposed: [b][h][d][t] bf16 (PV B-frags contiguous)
          vt[((size_t)(bb * NHEAD + h) * HD + d) * TSEQ + t] = f2bf(v);
        } else {
          float* dstp = (z == 0) ? qf : kf;
          dstp[((size_t)(bb * NHEAD + h) * TSEQ + t) * HD + d] = v;
        }
      }
}

// ---------------- output projection (flattened grid, XCD-chunked) ----------------
// 384 blocks = 32 m x 12 n; each XCD gets 8m x 6n.
__global__ __launch_bounds__(256) void gemm_out_kernel(const u16* __restrict__ yh,
                                                       const u16* __restrict__ wp,
                                                       float* __restrict__ out) {
  __shared__ __align__(16) u16 lA[3][4096], lW[3][4096];
  const int tid = threadIdx.x;
  const int wgid = blockIdx.x;
  const int xcd = wgid & 7, c = wgid >> 3;      // c in [0,48)
  const int m = ((xcd & 3) << 3) + (c & 7);     // 0..31
  const int n = ((xcd >> 2) * 6) + (c >> 3);    // 0..11
  const int M0 = m * 128, N0 = n * 128;
  f32x4_t acc[4][4] = {};
  gemm_mainloop(yh, wp, M0, N0, lA, lW, acc, tid);
  const int w = tid >> 6, l = tid & 63;
  const int lrow = l & 15, kg = l >> 4;
  const int wr = (w >> 1) * 64, wc = (w & 1) * 64;
#pragma unroll
  for (int mi = 0; mi < 4; ++mi)
#pragma unroll
    for (int ni = 0; ni < 4; ++ni)
#pragma unroll
      for (int r = 0; r < 4; ++r) {
        const int grow = M0 + wr + mi * 16 + kg * 4 + r;
        const int gcol = N0 + wc + ni * 16 + lrow;
        out[(size_t)grow * HIDDEN + gcol] = acc[mi][ni][r];
      }
}

// ---------------- RoPE + RMSNorm (fp32 in, bf16 out, head layout) ----------------
__global__ __launch_bounds__(256) void rope_rms_kernel(
    const float* __restrict__ qf, const float* __restrict__ kf, const float* __restrict__ cosp,
    const float* __restrict__ sinp, u16* __restrict__ qh, u16* __restrict__ kh) {
  const int w = threadIdx.x >> 6, l = threadIdx.x & 63;
  const int row = blockIdx.x * 4 + w;  // (b*NH+h)*T + t
  const int t = row & (TSEQ - 1);
  const float* src = blockIdx.y ? kf : qf;
  u16* dst = blockIdx.y ? kh : qh;
  const size_t base = (size_t)row * HD;
  float x1 = src[base + l];
  float x2 = src[base + 64 + l];
  float c = cosp[t * 64 + l], s = sinp[t * 64 + l];
  float y1 = x1 * c + x2 * s;
  float y2 = x2 * c - x1 * s;
  float ss = y1 * y1 + y2 * y2;
#pragma unroll
  for (int off = 1; off < 64; off <<= 1) ss += __shfl_xor(ss, off, 64);
  float rinv = rsqrtf(ss * (1.0f / 128.0f) + EPS_F);
  dst[base + l] = f2bf(y1 * rinv);
  dst[base + 64 + l] = f2bf(y2 * rinv);
}

// ---------------- flash attention, causal + sliding window ----------------
// (unchanged from round 4)
__global__ __launch_bounds__(256, 2) void attn_kernel(const u16* __restrict__ qh,
                                                      const u16* __restrict__ kh,
                                                      const u16* __restrict__ vt,
                                                      u16* __restrict__ yh,
                                                      const int* __restrict__ winp) {
  __shared__ __align__(16) u16 Kl[2][8192];  // [buf][64 keys x 128 d], row=256B, swizzled
  __shared__ __align__(16) u16 Vl[8192];     // [128 d x 64 t], row=128B, swizzled
  __shared__ __align__(16) u16 Pl[4][1024];  // per-wave 16x64 P, swizzled
  const int tid = threadIdx.x, w = tid >> 6, l = tid & 63;
  const int lrow = l & 15, kg = l >> 4;
  const int bid = blockIdx.x;
  const int swz = (bid & 7) * 96 + (bid >> 3);
  const int qb = swz & 31;   // q-block within (b,h)
  const int bh = swz >> 5;   // 0..23
  const int h = bh % NHEAD, b = bh / NHEAD;
  const int win = winp[0];
  const u16* Q = qh + (size_t)bh * TSEQ * HD;
  const u16* K = kh + (size_t)bh * TSEQ * HD;
  const u16* V = vt + (size_t)bh * HD * TSEQ;
  const int qw = qb * 64 + w * 16;  // this wave's 16 q-rows
  bf16x8_t aq[4];
#pragma unroll
  for (int ks = 0; ks < 4; ++ks)
    aq[ks] = *reinterpret_cast<const bf16x8_t*>(Q + (qw + lrow) * HD + ks * 32 + kg * 8);
  float lrun[4] = {0.f, 0.f, 0.f, 0.f};
  f32x4_t accv[8] = {};
  int lo = qb * 64 - win;
  if (lo < 0) lo = 0;
  lo &= ~63;
  const int last = qb * 64;  // last KV tile start (diagonal tile)
  u16* Pw = &Pl[w][0];

  auto stage_k = [&](int kv, int buf) {
#pragma unroll
    for (int i = 0; i < 4; ++i) {
      const int c = i * 256 + w * 64 + l;
      const int row = c >> 4, j = c & 15;
      const u16* src = K + (size_t)(kv + row) * HD + ((j ^ (row & 7)) * 8);
      __builtin_amdgcn_global_load_lds(
          (const __attribute__((address_space(1))) void*)src,
          (__attribute__((address_space(3))) void*)(&Kl[buf][0] + i * 2048 + w * 512), 16, 0, 0);
    }
  };
  auto stage_v = [&](int kv) {
#pragma unroll
    for (int i = 0; i < 4; ++i) {
      const int c = i * 256 + w * 64 + l;
      const int row = c >> 3, j = c & 7;
      const u16* src = V + (size_t)row * TSEQ + kv + ((j ^ (row & 7)) * 8);
      __builtin_amdgcn_global_load_lds(
          (const __attribute__((address_space(1))) void*)src,
          (__attribute__((address_space(3))) void*)(&Vl[0] + i * 2048 + w * 512), 16, 0, 0);
    }
  };

  stage_k(lo, 0);  // prologue: 4 loads in flight
  int it = 0;
  for (int kv = lo; kv <= last; kv += 64, ++it) {
    const int cur = it & 1;
    stage_v(kv);                // +4 (awaited this iter, after QK)
    stage_k(kv + 64, cur ^ 1);  // +4 prefetch (last iter reads harmless garbage)
    asm volatile("s_waitcnt vmcnt(8)" ::: "memory");  // K(kv) landed; V+Knext in flight
    __builtin_amdgcn_s_barrier();
    asm volatile("" ::: "memory");
    const u16* Kb = &Kl[cur][0];
    f32x4_t s[4] = {};
#pragma unroll
    for (int n = 0; n < 4; ++n) {
      const int row = n * 16 + lrow;
#pragma unroll
      for (int ks = 0; ks < 4; ++ks) {
        bf16x8_t bk = *reinterpret_cast<const bf16x8_t*>(
            Kb + row * 128 + (((ks << 2) | kg) ^ (row & 7)) * 8);
        s[n] = MFMA16(aq[ks], bk, s[n]);
      }
    }
    float ps[4][4];
    float psum[4];
#pragma unroll
    for (int n = 0; n < 4; ++n) {
      const int key = kv + n * 16 + lrow;
#pragma unroll
      for (int r = 0; r < 4; ++r) {
        const int rowq = qw + kg * 4 + r;
        const bool ok = (key <= rowq) && (rowq - key <= win);
        ps[n][r] = ok ? exp2f(__builtin_fmaf(s[n][r], SCALE_LOG2E, -FIXSUB)) : 0.0f;
      }
    }
#pragma unroll
    for (int r = 0; r < 4; ++r) psum[r] = (ps[0][r] + ps[1][r]) + (ps[2][r] + ps[3][r]);
#pragma unroll
    for (int off = 1; off < 16; off <<= 1)
#pragma unroll
      for (int r = 0; r < 4; ++r) psum[r] += __shfl_xor(psum[r], off, 64);
#pragma unroll
    for (int r = 0; r < 4; ++r) lrun[r] += psum[r];
#pragma unroll
    for (int n = 0; n < 4; ++n)
#pragma unroll
      for (int r = 0; r < 4; ++r) {
        const int rp = kg * 4 + r;
        int bofs = rp * 128 + (n * 16 + lrow) * 2;
        bofs ^= (rp & 7) << 4;
        *reinterpret_cast<u16*>(reinterpret_cast<char*>(Pw) + bofs) = f2bf(ps[n][r]);
      }
    asm volatile("s_waitcnt lgkmcnt(0)" ::: "memory");
    asm volatile("s_waitcnt vmcnt(4)" ::: "memory");  // V(kv) landed; Knext in flight
    __builtin_amdgcn_s_barrier();
    asm volatile("" ::: "memory");
    bf16x8_t ap[2];
#pragma unroll
    for (int k2 = 0; k2 < 2; ++k2) {
      int bofs = lrow * 128 + k2 * 64 + kg * 16;
      bofs ^= (lrow & 7) << 4;
      ap[k2] = *reinterpret_cast<const bf16x8_t*>(reinterpret_cast<const char*>(Pw) + bofs);
    }
#pragma unroll
    for (int k2 = 0; k2 < 2; ++k2)
#pragma unroll
      for (int dn = 0; dn < 8; ++dn) {
        const int row = dn * 16 + lrow;
        bf16x8_t bv = *reinterpret_cast<const bf16x8_t*>(
            Vl + row * 64 + (((k2 << 2) | kg) ^ (row & 7)) * 8);
        accv[dn] = MFMA16(ap[k2], bv, accv[dn]);
      }
    __builtin_amdgcn_s_barrier();  // Vl/Kl safe to restage next iter
    asm volatile("" ::: "memory");
  }
  float inv[4];
#pragma unroll
  for (int r = 0; r < 4; ++r) inv[r] = 1.0f / lrun[r];
#pragma unroll
  for (int dn = 0; dn < 8; ++dn)
#pragma unroll
    for (int r = 0; r < 4; ++r) {
      const int rowg = b * TSEQ + qw + kg * 4 + r;
      const int col = h * HD + dn * 16 + lrow;
      yh[(size_t)rowg * HIDDEN + col] = f2bf(accv[dn][r] * inv[r]);
    }
}

extern "C" void kernel_launch(void* const* d_in, const int* in_sizes, int n_in, void* d_out,
                              int out_size, void* d_ws, size_t ws_size, hipStream_t stream) {
  const float* x = (const float*)d_in[0];
  const float* cosp = (const float*)d_in[1];
  const float* sinp = (const float*)d_in[2];
  const float* Wq = (const float*)d_in[3];
  const float* Wk = (const float*)d_in[4];
  const float* Wv = (const float*)d_in[5];
  const float* Wp = (const float*)d_in[6];
  const int* winp = (const int*)d_in[7];

  char* ws = (char*)d_ws;
  size_t off = 0;
  auto alloc = [&](size_t bytes) {
    char* p = ws + off;
    off += (bytes + 255) & ~(size_t)255;
    return p;
  };
  u16* xb = (u16*)alloc((size_t)NROWS * HIDDEN * 2);
  u16* wqb = (u16*)alloc((size_t)HIDDEN * HIDDEN * 2);
  u16* wkb = (u16*)alloc((size_t)HIDDEN * HIDDEN * 2);
  u16* wvb = (u16*)alloc((size_t)HIDDEN * HIDDEN * 2);
  u16* wpb = (u16*)alloc((size_t)HIDDEN * HIDDEN * 2);
  float* qf = (float*)alloc((size_t)NROWS * HIDDEN * 4);
  float* kf = (float*)alloc((size_t)NROWS * HIDDEN * 4);
  u16* qh = (u16*)alloc((size_t)NROWS * HIDDEN * 2);
  u16* kh = (u16*)alloc((size_t)NROWS * HIDDEN * 2);
  u16* vt = (u16*)alloc((size_t)NROWS * HIDDEN * 2);
  u16* yh = (u16*)alloc((size_t)NROWS * HIDDEN * 2);

  const int nx = NROWS * HIDDEN;   // 6291456
  const int nw = HIDDEN * HIDDEN;  // 2359296
  cast_kernel<<<nx / 1024, 256, 0, stream>>>(x, xb, nx);
  cast4_kernel<<<dim3(nw / 1024, 4), 256, 0, stream>>>(Wq, Wk, Wv, Wp, wqb, wkb, wvb, wpb, nw);

  gemm_qkv_kernel<<<dim3(1152), 256, 0, stream>>>(xb, wqb, wkb, wvb, qf, kf, vt);
  rope_rms_kernel<<<dim3((2 * NHEAD * TSEQ) / 4, 2), 256, 0, stream>>>(qf, kf, cosp, sinp, qh,
                                                                       kh);
  attn_kernel<<<dim3(768), 256, 0, stream>>>(qh, kh, vt, yh, winp);
  gemm_out_kernel<<<dim3(384), 256, 0, stream>>>(yh, wpb, (float*)d_out);
}

// Round 6
// 212.182 us; speedup vs baseline: 1.2183x; 1.2183x over previous
//
#include <hip/hip_runtime.h>
#include <stdint.h>

#define HIDDEN 1536
#define NHEAD 12
#define HD 128
#define TSEQ 2048
#define NROWS 4096
#define KDIM HIDDEN
#define EPS_F 1.1920928955078125e-07f
// (1/sqrt(128)) * log2(e)
#define SCALE_LOG2E 0.12751879110195655f
// fixed softmax shift (log2 domain): scores bounded by sqrt(128)=11.314 (RMS-normed
// q,k => |q||k|<=128 by Cauchy-Schwarz), *log2(e) = 16.32; use 16.6 for bf16 margin.
#define FIXSUB 16.6f

typedef unsigned short u16;
typedef __bf16 bf16x8_t __attribute__((ext_vector_type(8)));
typedef float f32x4_t __attribute__((ext_vector_type(4)));

#define MFMA16(a, b, c) __builtin_amdgcn_mfma_f32_16x16x32_bf16((a), (b), (c), 0, 0, 0)

__device__ __forceinline__ u16 f2bf(float f) {
  unsigned u = __builtin_bit_cast(unsigned, f);
  u = (u + 0x7fffu + ((u >> 16) & 1u)) >> 16;
  return (u16)u;
}
__device__ __forceinline__ float bfu(u16 v) {
  return __builtin_bit_cast(float, ((unsigned)v) << 16);
}

// ---------------- cast fp32 -> bf16 (vectorized) ----------------
__global__ __launch_bounds__(256) void cast_kernel(const float* __restrict__ in,
                                                   u16* __restrict__ out, int n) {
  int i = (blockIdx.x * 256 + threadIdx.x) * 4;
  if (i >= n) return;
  float4 v = *reinterpret_cast<const float4*>(in + i);
  uint2 pk;
  pk.x = (unsigned)f2bf(v.x) | ((unsigned)f2bf(v.y) << 16);
  pk.y = (unsigned)f2bf(v.z) | ((unsigned)f2bf(v.w) << 16);
  *reinterpret_cast<uint2*>(out + i) = pk;
}

// 4 equal-size weight casts in one launch (blockIdx.y selects)
__global__ __launch_bounds__(256) void cast4_kernel(
    const float* __restrict__ a, const float* __restrict__ b, const float* __restrict__ c,
    const float* __restrict__ d, u16* __restrict__ oa, u16* __restrict__ ob,
    u16* __restrict__ oc, u16* __restrict__ od, int n) {
  const float* in;
  u16* out;
  switch (blockIdx.y) {
    case 0: in = a; out = oa; break;
    case 1: in = b; out = ob; break;
    case 2: in = c; out = oc; break;
    default: in = d; out = od; break;
  }
  int i = (blockIdx.x * 256 + threadIdx.x) * 4;
  if (i >= n) return;
  float4 v = *reinterpret_cast<const float4*>(in + i);
  uint2 pk;
  pk.x = (unsigned)f2bf(v.x) | ((unsigned)f2bf(v.y) << 16);
  pk.y = (unsigned)f2bf(v.z) | ((unsigned)f2bf(v.w) << 16);
  *reinterpret_cast<uint2*>(out + i) = pk;
}

// ---------------- shared NT-GEMM mainloop: C[128x128] = A[128xK] * W[128xK]^T ----------------
// Double-buffered LDS (round-4 structure) + incrementally-advanced source pointers
// (no per-iter address recomputation). lds layout: A bufs at [0,4096),[4096,8192);
// W bufs at [8192,12288),[12288,16384). bf16 in, fp32 acc.
__device__ __forceinline__ void gemm_mainloop(const u16* __restrict__ A,
                                              const u16* __restrict__ W, int M0, int N0,
                                              u16* lds, f32x4_t acc[4][4], int tid) {
  const int w = tid >> 6, l = tid & 63;
  const int lrow = l & 15, kg = l >> 4;
  const int wr = (w >> 1) * 64, wc = (w & 1) * 64;
  const int c0 = w * 128 + l;  // chunk ids (this thread stages chunks c0 and c0+64)
  const int c1 = c0 + 64;
  const u16* pa0 = A + (size_t)(M0 + (c0 >> 2)) * KDIM + (c0 & 3) * 8;
  const u16* pa1 = A + (size_t)(M0 + (c1 >> 2)) * KDIM + (c1 & 3) * 8;
  const u16* pw0 = W + (size_t)(N0 + (c0 >> 2)) * KDIM + (c0 & 3) * 8;
  const u16* pw1 = W + (size_t)(N0 + (c1 >> 2)) * KDIM + (c1 & 3) * 8;
  u16* dA = lds + w * 1024;
  u16* dW = lds + 8192 + w * 1024;
  auto issue = [&](int buf) {
    __builtin_amdgcn_global_load_lds((const __attribute__((address_space(1))) void*)pa0,
        (__attribute__((address_space(3))) void*)(dA + buf * 4096), 16, 0, 0);
    __builtin_amdgcn_global_load_lds((const __attribute__((address_space(1))) void*)pa1,
        (__attribute__((address_space(3))) void*)(dA + buf * 4096 + 512), 16, 0, 0);
    __builtin_amdgcn_global_load_lds((const __attribute__((address_space(1))) void*)pw0,
        (__attribute__((address_space(3))) void*)(dW + buf * 4096), 16, 0, 0);
    __builtin_amdgcn_global_load_lds((const __attribute__((address_space(1))) void*)pw1,
        (__attribute__((address_space(3))) void*)(dW + buf * 4096 + 512), 16, 0, 0);
    pa0 += 32; pa1 += 32; pw0 += 32; pw1 += 32;
  };
  issue(0);
  const int NT = KDIM / 32;  // 48
#pragma unroll 1
  for (int kt = 0; kt < NT; ++kt) {
    const int cur = kt & 1;
    if (kt + 1 < NT) {
      issue(cur ^ 1);
      asm volatile("s_waitcnt vmcnt(4)" ::: "memory");  // current buffer's 4 loads done
    } else {
      asm volatile("s_waitcnt vmcnt(0)" ::: "memory");
    }
    __builtin_amdgcn_s_barrier();
    asm volatile("" ::: "memory");
    const u16* Ab = lds + cur * 4096;
    const u16* Wb = lds + 8192 + cur * 4096;
    bf16x8_t af[4], bf_[4];
#pragma unroll
    for (int m = 0; m < 4; ++m)
      af[m] = *reinterpret_cast<const bf16x8_t*>(Ab + (wr + m * 16 + lrow) * 32 + kg * 8);
#pragma unroll
    for (int n = 0; n < 4; ++n)
      bf_[n] = *reinterpret_cast<const bf16x8_t*>(Wb + (wc + n * 16 + lrow) * 32 + kg * 8);
#pragma unroll
    for (int m = 0; m < 4; ++m)
#pragma unroll
      for (int n = 0; n < 4; ++n)
        acc[m][n] = MFMA16(af[m], bf_[n], acc[m][n]);
    asm volatile("s_waitcnt lgkmcnt(0)" ::: "memory");
    __builtin_amdgcn_s_barrier();
    asm volatile("" ::: "memory");
  }
}

// ---------------- QKV projection + fused RoPE/RMSNorm epilogue ----------------
// Grid 1152 flattened, XCD-chunked (8 XCDs x [8m x 18nz]); A-band L2-resident.
// Tile = 128 tokens x 128 dims = exactly one head: after the mainloop the C-tile
// is staged (bf16, XOR-swizzled) in the same 32KB LDS, then:
//   z=0/1: per-token RoPE + RMSNorm fully in-block -> qh/kh bf16 [bh][t][d]
//   z=2  : transposed -> vt bf16 [bh][d][t], coalesced 16B stores
__global__ __launch_bounds__(256) void gemm_qkv_kernel(
    const u16* __restrict__ xb, const u16* __restrict__ wq, const u16* __restrict__ wk,
    const u16* __restrict__ wv, const float* __restrict__ cosp, const float* __restrict__ sinp,
    u16* __restrict__ qh, u16* __restrict__ kh, u16* __restrict__ vt) {
  __shared__ __align__(16) u16 lds[16384];
  const int tid = threadIdx.x;
  const int wgid = blockIdx.x;
  const int xcd = wgid & 7, c = wgid >> 3;      // c in [0,144)
  const int m = ((xcd & 3) << 3) + (c & 7);     // 0..31
  const int nz = ((xcd >> 2) * 18) + (c >> 3);  // 0..35
  const int z = nz / 12, n = nz % 12;
  const int M0 = m * 128, N0 = n * 128;
  const u16* W = (z == 0) ? wq : (z == 1) ? wk : wv;
  f32x4_t acc[4][4] = {};
  gemm_mainloop(xb, W, M0, N0, lds, acc, tid);
  // ---- stage C tile as bf16 into LDS (mainloop's final barrier makes this safe) ----
  const int w = tid >> 6, l = tid & 63;
  const int lrow = l & 15, kg = l >> 4;
  const int wr = (w >> 1) * 64, wc = (w & 1) * 64;
  char* cs = reinterpret_cast<char*>(lds);
  if (z == 2) {
    // [d][t] layout: byte = d*256 + t*2, XOR bits4-6 with d&7 (bank spread)
#pragma unroll
    for (int mi = 0; mi < 4; ++mi)
#pragma unroll
      for (int ni = 0; ni < 4; ++ni)
#pragma unroll
        for (int r = 0; r < 4; ++r) {
          const int t_l = wr + mi * 16 + kg * 4 + r;
          const int d = wc + ni * 16 + lrow;
          const int bofs = (d * 256 + t_l * 2) ^ ((d & 7) << 4);
          *reinterpret_cast<u16*>(cs + bofs) = f2bf(acc[mi][ni][r]);
        }
  } else {
    // [t][d] layout: byte = t*256 + d*2, XOR with t&7
#pragma unroll
    for (int mi = 0; mi < 4; ++mi)
#pragma unroll
      for (int ni = 0; ni < 4; ++ni)
#pragma unroll
        for (int r = 0; r < 4; ++r) {
          const int t_l = wr + mi * 16 + kg * 4 + r;
          const int d = wc + ni * 16 + lrow;
          const int bofs = (t_l * 256 + d * 2) ^ ((t_l & 7) << 4);
          *reinterpret_cast<u16*>(cs + bofs) = f2bf(acc[mi][ni][r]);
        }
  }
  __syncthreads();
  const int rr = tid >> 1, hh = tid & 1;  // 256 threads: row 0..127, half 0/1
  const int bb = M0 >> 11;                // batch (tile never straddles)
  const int t0 = M0 & (TSEQ - 1);
  const size_t bhn = (size_t)(bb * NHEAD + n);
  if (z == 2) {
    // coalesced [d][t] store: thread covers d=rr, t = t0 + hh*64 + j*8..
    u16* dst = vt + (bhn * HD + rr) * TSEQ + t0 + hh * 64;
    const char* base = cs + rr * 256 + hh * 128;
#pragma unroll
    for (int j = 0; j < 8; ++j) {
      uint4 v = *reinterpret_cast<const uint4*>(base + ((j ^ (rr & 7)) * 16));
      *reinterpret_cast<uint4*>(dst + j * 8) = v;
    }
  } else {
    // RoPE + RMSNorm on token row rr (this thread: half hh = d in [hh*64, hh*64+64))
    const int t = (t0 + rr);  // global within batch: t0+rr < 2048
    const float* cosb = cosp + t * 64;
    const float* sinb = sinp + t * 64;
    const char* base = cs + rr * 256;
    float ss = 0.0f;
    unsigned pk[32];  // 64 rope'd values packed bf16x2
#pragma unroll
    for (int j = 0; j < 8; ++j) {
      const int jp = (j ^ (rr & 7)) * 16;
      uint4 vo = *reinterpret_cast<const uint4*>(base + hh * 128 + jp);        // own half
      uint4 vx = *reinterpret_cast<const uint4*>(base + (hh ^ 1) * 128 + jp);  // other half
      const unsigned vo32[4] = {vo.x, vo.y, vo.z, vo.w};
      const unsigned vx32[4] = {vx.x, vx.y, vx.z, vx.w};
      const float* cj = cosb + j * 8;
      const float* sj = sinb + j * 8;
#pragma unroll
      for (int q2 = 0; q2 < 4; ++q2) {
        float o0 = bfu((u16)(vo32[q2] & 0xffffu)), o1 = bfu((u16)(vo32[q2] >> 16));
        float x0 = bfu((u16)(vx32[q2] & 0xffffu)), x1 = bfu((u16)(vx32[q2] >> 16));
        float c0 = cj[q2 * 2], c1 = cj[q2 * 2 + 1];
        float s0 = sj[q2 * 2], s1 = sj[q2 * 2 + 1];
        // hh=0: y = x1*cos + x2*sin ; hh=1: y = x2*cos - x1*sin
        float y0 = hh ? __builtin_fmaf(o0, c0, -x0 * s0) : __builtin_fmaf(o0, c0, x0 * s0);
        float y1 = hh ? __builtin_fmaf(o1, c1, -x1 * s1) : __builtin_fmaf(o1, c1, x1 * s1);
        ss = __builtin_fmaf(y0, y0, __builtin_fmaf(y1, y1, ss));
        pk[j * 4 + q2] = (unsigned)f2bf(y0) | ((unsigned)f2bf(y1) << 16);
      }
    }
    ss += __shfl_xor(ss, 1, 64);  // partner thread holds the other half of this row
    const float rinv = rsqrtf(ss * (1.0f / 128.0f) + EPS_F);
    u16* dst = ((z == 0) ? qh : kh) + (bhn * TSEQ + t) * HD + hh * 64;
#pragma unroll
    for (int j = 0; j < 8; ++j) {
      unsigned o[4];
#pragma unroll
      for (int q2 = 0; q2 < 4; ++q2) {
        float y0 = bfu((u16)(pk[j * 4 + q2] & 0xffffu)) * rinv;
        float y1 = bfu((u16)(pk[j * 4 + q2] >> 16)) * rinv;
        o[q2] = (unsigned)f2bf(y0) | ((unsigned)f2bf(y1) << 16);
      }
      uint4 v;
      v.x = o[0]; v.y = o[1]; v.z = o[2]; v.w = o[3];
      *reinterpret_cast<uint4*>(dst + j * 8) = v;
    }
  }
}

// ---------------- output projection (flattened grid, XCD-chunked) ----------------
__global__ __launch_bounds__(256) void gemm_out_kernel(const u16* __restrict__ yh,
                                                       const u16* __restrict__ wp,
                                                       float* __restrict__ out) {
  __shared__ __align__(16) u16 lds[16384];
  const int tid = threadIdx.x;
  const int wgid = blockIdx.x;
  const int xcd = wgid & 7, c = wgid >> 3;    // c in [0,48)
  const int m = ((xcd & 3) << 3) + (c & 7);   // 0..31
  const int n = ((xcd >> 2) * 6) + (c >> 3);  // 0..11
  const int M0 = m * 128, N0 = n * 128;
  f32x4_t acc[4][4] = {};
  gemm_mainloop(yh, wp, M0, N0, lds, acc, tid);
  const int w = tid >> 6, l = tid & 63;
  const int lrow = l & 15, kg = l >> 4;
  const int wr = (w >> 1) * 64, wc = (w & 1) * 64;
#pragma unroll
  for (int mi = 0; mi < 4; ++mi)
#pragma unroll
    for (int ni = 0; ni < 4; ++ni)
#pragma unroll
      for (int r = 0; r < 4; ++r) {
        const int grow = M0 + wr + mi * 16 + kg * 4 + r;
        const int gcol = N0 + wc + ni * 16 + lrow;
        out[(size_t)grow * HIDDEN + gcol] = acc[mi][ni][r];
      }
}

// ---------------- flash attention, causal + sliding window ----------------
// (unchanged from round 4)
__global__ __launch_bounds__(256, 2) void attn_kernel(const u16* __restrict__ qh,
                                                      const u16* __restrict__ kh,
                                                      const u16* __restrict__ vt,
                                                      u16* __restrict__ yh,
                                                      const int* __restrict__ winp) {
  __shared__ __align__(16) u16 Kl[2][8192];  // [buf][64 keys x 128 d], row=256B, swizzled
  __shared__ __align__(16) u16 Vl[8192];     // [128 d x 64 t], row=128B, swizzled
  __shared__ __align__(16) u16 Pl[4][1024];  // per-wave 16x64 P, swizzled
  const int tid = threadIdx.x, w = tid >> 6, l = tid & 63;
  const int lrow = l & 15, kg = l >> 4;
  const int bid = blockIdx.x;
  const int swz = (bid & 7) * 96 + (bid >> 3);
  const int qb = swz & 31;  // q-block within (b,h)
  const int bh = swz >> 5;  // 0..23
  const int h = bh % NHEAD, b = bh / NHEAD;
  const int win = winp[0];
  const u16* Q = qh + (size_t)bh * TSEQ * HD;
  const u16* K = kh + (size_t)bh * TSEQ * HD;
  const u16* V = vt + (size_t)bh * HD * TSEQ;
  const int qw = qb * 64 + w * 16;  // this wave's 16 q-rows
  bf16x8_t aq[4];
#pragma unroll
  for (int ks = 0; ks < 4; ++ks)
    aq[ks] = *reinterpret_cast<const bf16x8_t*>(Q + (qw + lrow) * HD + ks * 32 + kg * 8);
  float lrun[4] = {0.f, 0.f, 0.f, 0.f};
  f32x4_t accv[8] = {};
  int lo = qb * 64 - win;
  if (lo < 0) lo = 0;
  lo &= ~63;
  const int last = qb * 64;  // last KV tile start (diagonal tile)
  u16* Pw = &Pl[w][0];

  auto stage_k = [&](int kv, int buf) {
#pragma unroll
    for (int i = 0; i < 4; ++i) {
      const int c = i * 256 + w * 64 + l;
      const int row = c >> 4, j = c & 15;
      const u16* src = K + (size_t)(kv + row) * HD + ((j ^ (row & 7)) * 8);
      __builtin_amdgcn_global_load_lds(
          (const __attribute__((address_space(1))) void*)src,
          (__attribute__((address_space(3))) void*)(&Kl[buf][0] + i * 2048 + w * 512), 16, 0, 0);
    }
  };
  auto stage_v = [&](int kv) {
#pragma unroll
    for (int i = 0; i < 4; ++i) {
      const int c = i * 256 + w * 64 + l;
      const int row = c >> 3, j = c & 7;
      const u16* src = V + (size_t)row * TSEQ + kv + ((j ^ (row & 7)) * 8);
      __builtin_amdgcn_global_load_lds(
          (const __attribute__((address_space(1))) void*)src,
          (__attribute__((address_space(3))) void*)(&Vl[0] + i * 2048 + w * 512), 16, 0, 0);
    }
  };

  stage_k(lo, 0);  // prologue: 4 loads in flight
  int it = 0;
  for (int kv = lo; kv <= last; kv += 64, ++it) {
    const int cur = it & 1;
    stage_v(kv);                // +4 (awaited this iter, after QK)
    stage_k(kv + 64, cur ^ 1);  // +4 prefetch (last iter reads harmless garbage)
    asm volatile("s_waitcnt vmcnt(8)" ::: "memory");  // K(kv) landed; V+Knext in flight
    __builtin_amdgcn_s_barrier();
    asm volatile("" ::: "memory");
    const u16* Kb = &Kl[cur][0];
    f32x4_t s[4] = {};
#pragma unroll
    for (int n = 0; n < 4; ++n) {
      const int row = n * 16 + lrow;
#pragma unroll
      for (int ks = 0; ks < 4; ++ks) {
        bf16x8_t bk = *reinterpret_cast<const bf16x8_t*>(
            Kb + row * 128 + (((ks << 2) | kg) ^ (row & 7)) * 8);
        s[n] = MFMA16(aq[ks], bk, s[n]);
      }
    }
    float ps[4][4];
    float psum[4];
#pragma unroll
    for (int n = 0; n < 4; ++n) {
      const int key = kv + n * 16 + lrow;
#pragma unroll
      for (int r = 0; r < 4; ++r) {
        const int rowq = qw + kg * 4 + r;
        const bool ok = (key <= rowq) && (rowq - key <= win);
        ps[n][r] = ok ? exp2f(__builtin_fmaf(s[n][r], SCALE_LOG2E, -FIXSUB)) : 0.0f;
      }
    }
#pragma unroll
    for (int r = 0; r < 4; ++r) psum[r] = (ps[0][r] + ps[1][r]) + (ps[2][r] + ps[3][r]);
#pragma unroll
    for (int off = 1; off < 16; off <<= 1)
#pragma unroll
      for (int r = 0; r < 4; ++r) psum[r] += __shfl_xor(psum[r], off, 64);
#pragma unroll
    for (int r = 0; r < 4; ++r) lrun[r] += psum[r];
#pragma unroll
    for (int n = 0; n < 4; ++n)
#pragma unroll
      for (int r = 0; r < 4; ++r) {
        const int rp = kg * 4 + r;
        int bofs = rp * 128 + (n * 16 + lrow) * 2;
        bofs ^= (rp & 7) << 4;
        *reinterpret_cast<u16*>(reinterpret_cast<char*>(Pw) + bofs) = f2bf(ps[n][r]);
      }
    asm volatile("s_waitcnt lgkmcnt(0)" ::: "memory");
    asm volatile("s_waitcnt vmcnt(4)" ::: "memory");  // V(kv) landed; Knext in flight
    __builtin_amdgcn_s_barrier();
    asm volatile("" ::: "memory");
    bf16x8_t ap[2];
#pragma unroll
    for (int k2 = 0; k2 < 2; ++k2) {
      int bofs = lrow * 128 + k2 * 64 + kg * 16;
      bofs ^= (lrow & 7) << 4;
      ap[k2] = *reinterpret_cast<const bf16x8_t*>(reinterpret_cast<const char*>(Pw) + bofs);
    }
#pragma unroll
    for (int k2 = 0; k2 < 2; ++k2)
#pragma unroll
      for (int dn = 0; dn < 8; ++dn) {
        const int row = dn * 16 + lrow;
        bf16x8_t bv = *reinterpret_cast<const bf16x8_t*>(
            Vl + row * 64 + (((k2 << 2) | kg) ^ (row & 7)) * 8);
        accv[dn] = MFMA16(ap[k2], bv, accv[dn]);
      }
    __builtin_amdgcn_s_barrier();  // Vl/Kl safe to restage next iter
    asm volatile("" ::: "memory");
  }
  float inv[4];
#pragma unroll
  for (int r = 0; r < 4; ++r) inv[r] = 1.0f / lrun[r];
#pragma unroll
  for (int dn = 0; dn < 8; ++dn)
#pragma unroll
    for (int r = 0; r < 4; ++r) {
      const int rowg = b * TSEQ + qw + kg * 4 + r;
      const int col = h * HD + dn * 16 + lrow;
      yh[(size_t)rowg * HIDDEN + col] = f2bf(accv[dn][r] * inv[r]);
    }
}

extern "C" void kernel_launch(void* const* d_in, const int* in_sizes, int n_in, void* d_out,
                              int out_size, void* d_ws, size_t ws_size, hipStream_t stream) {
  const float* x = (const float*)d_in[0];
  const float* cosp = (const float*)d_in[1];
  const float* sinp = (const float*)d_in[2];
  const float* Wq = (const float*)d_in[3];
  const float* Wk = (const float*)d_in[4];
  const float* Wv = (const float*)d_in[5];
  const float* Wp = (const float*)d_in[6];
  const int* winp = (const int*)d_in[7];

  char* ws = (char*)d_ws;
  size_t off = 0;
  auto alloc = [&](size_t bytes) {
    char* p = ws + off;
    off += (bytes + 255) & ~(size_t)255;
    return p;
  };
  u16* xb = (u16*)alloc((size_t)NROWS * HIDDEN * 2);
  u16* wqb = (u16*)alloc((size_t)HIDDEN * HIDDEN * 2);
  u16* wkb = (u16*)alloc((size_t)HIDDEN * HIDDEN * 2);
  u16* wvb = (u16*)alloc((size_t)HIDDEN * HIDDEN * 2);
  u16* wpb = (u16*)alloc((size_t)HIDDEN * HIDDEN * 2);
  u16* qh = (u16*)alloc((size_t)NROWS * HIDDEN * 2);
  u16* kh = (u16*)alloc((size_t)NROWS * HIDDEN * 2);
  u16* vt = (u16*)alloc((size_t)NROWS * HIDDEN * 2);
  u16* yh = (u16*)alloc((size_t)NROWS * HIDDEN * 2);

  const int nx = NROWS * HIDDEN;   // 6291456
  const int nw = HIDDEN * HIDDEN;  // 2359296
  cast_kernel<<<nx / 1024, 256, 0, stream>>>(x, xb, nx);
  cast4_kernel<<<dim3(nw / 1024, 4), 256, 0, stream>>>(Wq, Wk, Wv, Wp, wqb, wkb, wvb, wpb, nw);

  gemm_qkv_kernel<<<dim3(1152), 256, 0, stream>>>(xb, wqb, wkb, wvb, cosp, sinp, qh, kh, vt);
  attn_kernel<<<dim3(768), 256, 0, stream>>>(qh, kh, vt, yh, winp);
  gemm_out_kernel<<<dim3(384), 256, 0, stream>>>(yh, wpb, (float*)d_out);
}